// Round 3
// baseline (606.450 us; speedup 1.0000x reference)
//
#include <hip/hip_runtime.h>

// GRU stack (L=6, H=2048, batch=1) + LayerNorm + Linear. ALL fp32.
// Key insight: gh[l] = W_hh[l]@hidden[l] + b_hh depends only on the INPUT
// hidden state (not the layer chain), and gi[0] = W_ih[0]@x is also known
// upfront. So 352 MB of the 604 MB weight traffic runs in ONE fully
// parallel launch; only 5 x 50 MB W_ih matvecs remain serialized.

constexpr int HID  = 2048;
constexpr int G3   = 3 * HID;          // 6144
constexpr int NGH  = 6 * G3;           // 36864 gh rows
constexpr int NROW = NGH + G3;         // + 6144 gi0 rows = 43008

__device__ __forceinline__ float wave_sum(float s){
  #pragma unroll
  for(int off = 32; off; off >>= 1) s += __shfl_down(s, off, 64);
  return s;  // lane 0 holds total
}

// 2048-length fp32 dot by one wave: 8 x float4 per lane, fully unrolled
__device__ __forceinline__ float dot_f32(const float* __restrict__ row,
                                         const float* __restrict__ v, int lane){
  const float4* r4 = (const float4*)row;
  const float4* v4 = (const float4*)v;
  float s = 0.f;
  #pragma unroll
  for(int it = 0; it < 8; ++it){
    int idx = lane + 64 * it;
    float4 w = r4[idx], a = v4[idx];
    s += w.x * a.x + w.y * a.y + w.z * a.z + w.w * a.w;
  }
  return s;
}

__device__ __forceinline__ float sigm(float v){ return 1.f / (1.f + __expf(-v)); }

// ---- Kernel A: all gh rows (6 layers) + gi rows of layer 0, fully parallel.
// One wave per row, 8 waves/block, 5376 blocks.
__global__ __launch_bounds__(512) void k_par_matvec(
    const float* __restrict__ w_ih,   // [6][6144][2048] (layer 0 used)
    const float* __restrict__ w_hh,   // [6][6144][2048]
    const float* __restrict__ b_ih,   // [6][6144]
    const float* __restrict__ b_hh,   // [6][6144]
    const float* __restrict__ x,      // [2048]
    const float* __restrict__ hidden, // [6][2048]
    float* __restrict__ gh_all,       // ws [6][6144]
    float* __restrict__ gi0)          // ws [6144]
{
  int t    = blockIdx.x * 8 + (threadIdx.x >> 6);
  int lane = threadIdx.x & 63;
  if(t >= NROW) return;
  const float *row, *v;
  float bias; float* dst;
  if(t < NGH){
    int l = t / G3, r = t % G3;
    row  = w_hh + ((size_t)l * G3 + r) * HID;
    v    = hidden + l * HID;
    bias = b_hh[l * G3 + r];
    dst  = gh_all + l * G3 + r;
  } else {
    int r = t - NGH;
    row  = w_ih + (size_t)r * HID;   // layer 0
    v    = x;
    bias = b_ih[r];
    dst  = gi0 + r;
  }
  float s = wave_sum(dot_f32(row, v, lane));
  if(lane == 0) *dst = s + bias;
}

// ---- Layer-0 cell update (gi0 and gh0 both precomputed, biases included)
__global__ __launch_bounds__(256) void k_cell0(
    const float* __restrict__ gi0, const float* __restrict__ gh0,
    const float* __restrict__ h_orig,
    float* __restrict__ h_ws, float* __restrict__ h_out)
{
  int j = blockIdx.x * 256 + threadIdx.x;
  float r  = sigm(gi0[j] + gh0[j]);
  float z  = sigm(gi0[HID + j] + gh0[HID + j]);
  float n  = tanhf(gi0[2 * HID + j] + r * gh0[2 * HID + j]);
  float hn = (1.f - z) * n + z * h_orig[j];
  h_ws[j] = hn; h_out[j] = hn;
}

// ---- Layers 1..5: gi matvec + cell update. Block = 6 waves = 2 adjacent j,
// 3 gate-rows each. 1024 blocks.
__global__ __launch_bounds__(384) void k_gi_cell(
    const float* __restrict__ w_ih_l,  // [6144][2048]
    const float* __restrict__ b_ih_l,  // [6144]
    const float* __restrict__ gh_l,    // [6144] precomputed (b_hh included)
    const float* __restrict__ h_orig,  // hidden[l]
    const float* __restrict__ inp,     // chain h_{l-1}
    float* __restrict__ h_ws, float* __restrict__ h_out)
{
  int half  = threadIdx.x >= 192;          // which j of the pair
  int gate  = (threadIdx.x >> 6) % 3;      // 0..2
  int lane  = threadIdx.x & 63;
  int j     = blockIdx.x * 2 + half;
  __shared__ float sums[2][3];
  float s = wave_sum(dot_f32(w_ih_l + ((size_t)gate * HID + j) * HID, inp, lane));
  if(lane == 0) sums[half][gate] = s;
  __syncthreads();
  if(lane == 0 && gate == 0){              // threads 0 and 192
    float gi_r = sums[half][0] + b_ih_l[j];
    float gi_z = sums[half][1] + b_ih_l[HID + j];
    float gi_n = sums[half][2] + b_ih_l[2 * HID + j];
    float r  = sigm(gi_r + gh_l[j]);
    float z  = sigm(gi_z + gh_l[HID + j]);
    float n  = tanhf(gi_n + r * gh_l[2 * HID + j]);
    float hn = (1.f - z) * n + z * h_orig[j];
    h_ws[j] = hn; h_out[j] = hn;
  }
}

__global__ __launch_bounds__(256) void k_layernorm(
    const float* __restrict__ h,
    const float* __restrict__ gamma,
    const float* __restrict__ beta,
    float* __restrict__ out)
{
  __shared__ float rs[4], rs2[4];
  __shared__ float s_mu, s_istd;
  int wave = threadIdx.x >> 6, lane = threadIdx.x & 63;
  float s = 0.f, s2 = 0.f;
  for(int i = threadIdx.x; i < HID; i += 256){ float v = h[i]; s += v; s2 += v * v; }
  #pragma unroll
  for(int off = 32; off; off >>= 1){ s += __shfl_down(s, off, 64); s2 += __shfl_down(s2, off, 64); }
  if(lane == 0){ rs[wave] = s; rs2[wave] = s2; }
  __syncthreads();
  if(threadIdx.x == 0){
    float S  = rs[0] + rs[1] + rs[2] + rs[3];
    float S2 = rs2[0] + rs2[1] + rs2[2] + rs2[3];
    float m   = S * (1.f / HID);
    float var = S2 * (1.f / HID) - m * m;
    s_mu = m; s_istd = rsqrtf(var + 1e-5f);
  }
  __syncthreads();
  float mu = s_mu, istd = s_istd;
  for(int i = threadIdx.x; i < HID; i += 256){
    out[i] = (h[i] - mu) * istd * gamma[i] + beta[i];
  }
}

// pred[o] = ln_out . lin_w[o] + lin_b[o] + x[o]; one wave per row
__global__ __launch_bounds__(256) void k_linear(
    const float* __restrict__ v,
    const float* __restrict__ lin_w,
    const float* __restrict__ lin_b,
    const float* __restrict__ x,
    float* __restrict__ pred)
{
  int o    = blockIdx.x * 4 + (threadIdx.x >> 6);
  int lane = threadIdx.x & 63;
  float s = wave_sum(dot_f32(lin_w + (size_t)o * HID, v, lane));
  if(lane == 0) pred[o] = s + lin_b[o] + x[o];
}

extern "C" void kernel_launch(void* const* d_in, const int* in_sizes, int n_in,
                              void* d_out, int out_size, void* d_ws, size_t ws_size,
                              hipStream_t stream){
  const float* x      = (const float*)d_in[0];
  const float* hidden = (const float*)d_in[1];
  const float* w_ih   = (const float*)d_in[2];
  const float* w_hh   = (const float*)d_in[3];
  const float* b_ih   = (const float*)d_in[4];
  const float* b_hh   = (const float*)d_in[5];
  const float* gamma  = (const float*)d_in[6];
  const float* beta   = (const float*)d_in[7];
  const float* lin_w  = (const float*)d_in[8];
  const float* lin_b  = (const float*)d_in[9];
  float* out = (float*)d_out;  // [pred(2048) | new_hidden(6*2048)]

  float* buf     = (float*)d_ws;
  float* gh_all  = buf;                 // 6*6144
  float* gi0     = buf + NGH;           // 6144
  float* h_chain = buf + NROW;          // 6*2048
  float* ln_out  = buf + NROW + 6*HID;  // 2048

  // 1) All W_hh matvecs (6 layers) + W_ih layer-0 matvec, fully parallel.
  k_par_matvec<<<(NROW + 7) / 8, 512, 0, stream>>>(
      w_ih, w_hh, b_ih, b_hh, x, hidden, gh_all, gi0);

  // 2) Layer-0 cell update (no matvec left).
  k_cell0<<<HID / 256, 256, 0, stream>>>(gi0, gh_all, hidden, h_chain, out + HID);

  // 3) Layers 1..5: serialized gi matvec + cell update.
  for(int l = 1; l < 6; ++l){
    k_gi_cell<<<HID / 2, 384, 0, stream>>>(
        w_ih + (size_t)l * G3 * HID,
        b_ih + (size_t)l * G3,
        gh_all + (size_t)l * G3,
        hidden + (size_t)l * HID,
        h_chain + (size_t)(l - 1) * HID,
        h_chain + (size_t)l * HID,
        out + HID + (size_t)l * HID);
  }

  // 4) LayerNorm on top-layer output, then linear head + residual.
  k_layernorm<<<1, 256, 0, stream>>>(h_chain + 5 * HID, gamma, beta, ln_out);
  k_linear<<<HID / 4, 256, 0, stream>>>(ln_out, lin_w, lin_b, x, out);
}